// Round 1
// baseline (681.767 us; speedup 1.0000x reference)
//
#include <hip/hip_runtime.h>
#include <hip/hip_bf16.h>
#include <cstdint>

// Problem constants (B, L, D, H from the reference)
#define BB 4
#define LL 4096
#define DD 1024
#define HH 16
#define DKH 64
#define MROWS 16384   // B*L
#define KTOP 8

typedef float f32x4 __attribute__((ext_vector_type(4)));
typedef _Float16 f16;
typedef _Float16 f16x4 __attribute__((ext_vector_type(4)));
typedef _Float16 f16x8 __attribute__((ext_vector_type(8)));

// ---------------------------------------------------------------------------
// async global->LDS (16B per lane, wave-uniform LDS base + lane*16)
__device__ __forceinline__ void gll16(const void* g, void* l) {
    __builtin_amdgcn_global_load_lds(
        (const __attribute__((address_space(1))) void*)g,
        (__attribute__((address_space(3))) void*)l, 16, 0, 0);
}

// ---------------------------------------------------------------------------
// Per-head column means of Wq/Wk (mean over DK cols of each head) -> Wqm_t[h][d]
// plus per-head means of bq/bk. Exactness here protects top-k selection.
__global__ void k_colmeans(const float* __restrict__ Wq, const float* __restrict__ bq,
                           const float* __restrict__ Wk, const float* __restrict__ bk,
                           float* __restrict__ Wqm_t, float* __restrict__ Wkm_t,
                           float* __restrict__ bqm, float* __restrict__ bkm) {
    int t = blockIdx.x * blockDim.x + threadIdx.x;   // 0..32767
    int which = t >> 14;                             // 0=q 1=k
    int idx = t & 16383;
    int d = idx >> 4;
    int h = idx & 15;
    const float* W = which ? Wk : Wq;
    const float* p = W + d * DD + h * DKH;
    float s = 0.f;
    #pragma unroll
    for (int c = 0; c < DKH; ++c) s += p[c];
    (which ? Wkm_t : Wqm_t)[h * DD + d] = s * (1.0f / DKH);
    if (d == 0) {
        const float* bb = which ? bk : bq;
        float sb = 0.f;
        for (int c = 0; c < DKH; ++c) sb += bb[h * DKH + c];
        (which ? bkm : bqm)[h] = sb * (1.0f / DKH);
    }
}

// ---------------------------------------------------------------------------
// Transpose 1024x1024 fp32 -> f16 (out[n][k] = in[k][n]) via LDS tile.
__global__ void k_transpose_cvt(const float* __restrict__ in, f16* __restrict__ out) {
    __shared__ float tile[32][33];
    int k0 = blockIdx.x * 32;
    int n0 = blockIdx.y * 32;
    int tx = threadIdx.x, ty = threadIdx.y;
    #pragma unroll
    for (int j = 0; j < 32; j += 8)
        tile[ty + j][tx] = in[(k0 + ty + j) * DD + n0 + tx];
    __syncthreads();
    #pragma unroll
    for (int j = 0; j < 32; j += 8)
        out[(n0 + ty + j) * DD + k0 + tx] = (f16)tile[tx][ty + j];
}

// fp32 -> f16, 4 elems/thread
__global__ void k_cvt_f16(const float* __restrict__ in, f16* __restrict__ out) {
    int i = blockIdx.x * blockDim.x + threadIdx.x;
    f32x4 v = ((const f32x4*)in)[i];
    f16x4 o;
    o[0] = (f16)v.x; o[1] = (f16)v.y; o[2] = (f16)v.z; o[3] = (f16)v.w;
    ((f16x4*)out)[i] = o;
}

// ---------------------------------------------------------------------------
// qm[bh][l], km[bh][l]: fp32 dot of input row with per-head mean weights.
__global__ void k_means(const float* __restrict__ q, const float* __restrict__ k,
                        const float* __restrict__ Wqm_t, const float* __restrict__ Wkm_t,
                        const float* __restrict__ bqm, const float* __restrict__ bkm,
                        float* __restrict__ qm, float* __restrict__ km) {
    int t = blockIdx.x * 256 + threadIdx.x;   // 262144 threads
    int h = t & 15;
    int r = t >> 4;                           // 0..16383
    const f32x4* qr = (const f32x4*)(q + (size_t)r * DD);
    const f32x4* kr = (const f32x4*)(k + (size_t)r * DD);
    const f32x4* wq = (const f32x4*)(Wqm_t + h * DD);
    const f32x4* wk = (const f32x4*)(Wkm_t + h * DD);
    float sq = 0.f, sk = 0.f;
    #pragma unroll 4
    for (int i = 0; i < DD / 4; ++i) {
        f32x4 a = qr[i], b = kr[i], wa = wq[i], wb = wk[i];
        sq += a.x * wa.x + a.y * wa.y + a.z * wa.z + a.w * wa.w;
        sk += b.x * wb.x + b.y * wb.y + b.z * wb.z + b.w * wb.w;
    }
    int bh = (r >> 12) * HH + h;
    int l = r & 4095;
    qm[bh * LL + l] = sq + bqm[h];
    km[bh * LL + l] = sk + bkm[h];
}

// ---------------------------------------------------------------------------
// Direct circular correlation: corr[bh][d] = sum_m qm[bh][(m+d)%L] * km[bh][m]
// 256 blocks: block = (bh, 1024-lag range); thread = 4 consecutive lags,
// sliding 8-float register window, 16 FMA per 2 ds_read_b128.
__global__ __launch_bounds__(256) void k_corr(const float* __restrict__ qm,
                                              const float* __restrict__ km,
                                              float* __restrict__ corr) {
    __shared__ float sq[LL];
    __shared__ float sk[LL];
    int bh = blockIdx.x >> 2;
    int lag0 = (blockIdx.x & 3) * 1024;
    const f32x4* qg = (const f32x4*)(qm + bh * LL);
    const f32x4* kg = (const f32x4*)(km + bh * LL);
    f32x4* sq4 = (f32x4*)sq;
    f32x4* sk4 = (f32x4*)sk;
    for (int i = threadIdx.x; i < LL / 4; i += 256) { sq4[i] = qg[i]; sk4[i] = kg[i]; }
    __syncthreads();
    int d0 = lag0 + threadIdx.x * 4;   // aligned to 4
    float a0 = 0, a1 = 0, a2 = 0, a3 = 0;
    f32x4 wv = sq4[d0 >> 2];
    float w0 = wv.x, w1 = wv.y, w2 = wv.z, w3 = wv.w;
    #pragma unroll 4
    for (int m = 0; m < LL; m += 4) {
        f32x4 nx = sq4[((m + 4 + d0) & 4095) >> 2];
        f32x4 kv = sk4[m >> 2];
        a0 += kv.x * w0;  a1 += kv.x * w1;  a2 += kv.x * w2;  a3 += kv.x * w3;
        a0 += kv.y * w1;  a1 += kv.y * w2;  a2 += kv.y * w3;  a3 += kv.y * nx.x;
        a0 += kv.z * w2;  a1 += kv.z * w3;  a2 += kv.z * nx.x; a3 += kv.z * nx.y;
        a0 += kv.w * w3;  a1 += kv.w * nx.x; a2 += kv.w * nx.y; a3 += kv.w * nx.z;
        w0 = nx.x; w1 = nx.y; w2 = nx.z; w3 = nx.w;
    }
    f32x4 r; r.x = a0; r.y = a1; r.z = a2; r.w = a3;
    *(f32x4*)(corr + bh * LL + d0) = r;
}

// ---------------------------------------------------------------------------
// top-8 (value, index) per bh with lowest-index tie-break, then softmax.
__global__ __launch_bounds__(256) void k_topk(const float* __restrict__ corr,
                                              float* __restrict__ wts, int* __restrict__ dls) {
    __shared__ float sc[LL];
    __shared__ float rv[4]; __shared__ int ri[4];
    __shared__ float topv[KTOP]; __shared__ int topi[KTOP];
    int bh = blockIdx.x;
    for (int i = threadIdx.x; i < LL; i += 256) sc[i] = corr[bh * LL + i];
    for (int kk = 0; kk < KTOP; ++kk) {
        __syncthreads();
        float bv = -1e30f; int bi = 0;
        for (int i = threadIdx.x; i < LL; i += 256) {
            float v = sc[i];
            if (v > bv) { bv = v; bi = i; }
        }
        #pragma unroll
        for (int off = 32; off; off >>= 1) {
            float ov = __shfl_down(bv, off);
            int oi = __shfl_down(bi, off);
            if (ov > bv || (ov == bv && oi < bi)) { bv = ov; bi = oi; }
        }
        int wid = threadIdx.x >> 6;
        if ((threadIdx.x & 63) == 0) { rv[wid] = bv; ri[wid] = bi; }
        __syncthreads();
        if (threadIdx.x == 0) {
            for (int w = 1; w < 4; ++w)
                if (rv[w] > bv || (rv[w] == bv && ri[w] < bi)) { bv = rv[w]; bi = ri[w]; }
            topv[kk] = bv; topi[kk] = bi;
            sc[bi] = -1e30f;
        }
    }
    __syncthreads();
    if (threadIdx.x == 0) {
        float mx = topv[0], s = 0.f, e[KTOP];
        #pragma unroll
        for (int kk = 0; kk < KTOP; ++kk) { e[kk] = __expf(topv[kk] - mx); s += e[kk]; }
        float inv = 1.0f / s;
        #pragma unroll
        for (int kk = 0; kk < KTOP; ++kk) {
            wts[bh * KTOP + kk] = e[kk] * inv;
            dls[bh * KTOP + kk] = topi[kk];
        }
    }
}

// ---------------------------------------------------------------------------
// f16 MFMA GEMM, C = A(MxK) @ BT(NxK)^T + bias. 128x128 tile, BK=32, 4 waves.
// LDS tiles stored as 16B chunks row-major with XOR swizzle kc^((row>>1)&3):
// staging stays 64B-coalesced, fragment ds_read_b128 is 2-way (free).
// MODE 0: store f16 into V[b][h][l][c] (BHLD).  MODE 1: store fp32 row-major.
#define BM 128
#define BN 128
#define BKK 32
template <int MODE>
__global__ __launch_bounds__(256) void k_gemm_bt(const f16* __restrict__ A,
                                                 const f16* __restrict__ BT,
                                                 const float* __restrict__ bias,
                                                 void* __restrict__ Cout) {
    __shared__ f16 As[BM * BKK];   // 8 KB
    __shared__ f16 Bs[BN * BKK];   // 8 KB
    const int K = DD;
    int n0 = blockIdx.x * BN;
    int m0 = blockIdx.y * BM;
    int tid = threadIdx.x;
    int lane = tid & 63;
    int wave = tid >> 6;
    int wm = wave & 1, wn = wave >> 1;

    // staging source (two passes of 256 chunks)
    int row0 = tid >> 2;                 // 0..63
    int slot = tid & 3;
    int kc0 = slot ^ ((row0 >> 1) & 3);
    int row1 = row0 + 64;                // 64..127
    int kc1 = slot ^ ((row1 >> 1) & 3);
    const f16* gA0 = A + (size_t)(m0 + row0) * K + kc0 * 8;
    const f16* gA1 = A + (size_t)(m0 + row1) * K + kc1 * 8;
    const f16* gB0 = BT + (size_t)(n0 + row0) * K + kc0 * 8;
    const f16* gB1 = BT + (size_t)(n0 + row1) * K + kc1 * 8;
    char* ldsA0 = (char*)As + wave * 1024;
    char* ldsA1 = (char*)As + 4096 + wave * 1024;
    char* ldsB0 = (char*)Bs + wave * 1024;
    char* ldsB1 = (char*)Bs + 4096 + wave * 1024;

    // fragment LDS element offsets (constant per lane)
    int fr = lane & 15;
    int quad = lane >> 4;
    int a_off[4], b_off[4];
    #pragma unroll
    for (int i = 0; i < 4; ++i) {
        int ra = wm * 64 + i * 16 + fr;
        a_off[i] = (ra * 4 + (quad ^ ((ra >> 1) & 3))) * 8;
        int rb = wn * 64 + i * 16 + fr;
        b_off[i] = (rb * 4 + (quad ^ ((rb >> 1) & 3))) * 8;
    }

    f32x4 acc[4][4] = {};
    for (int kt = 0; kt < K; kt += BKK) {
        __syncthreads();
        gll16(gA0, ldsA0);
        gll16(gA1, ldsA1);
        gll16(gB0, ldsB0);
        gll16(gB1, ldsB1);
        gA0 += BKK; gA1 += BKK; gB0 += BKK; gB1 += BKK;
        __syncthreads();
        f16x8 af[4], bf[4];
        #pragma unroll
        for (int i = 0; i < 4; ++i) af[i] = *(const f16x8*)(As + a_off[i]);
        #pragma unroll
        for (int i = 0; i < 4; ++i) bf[i] = *(const f16x8*)(Bs + b_off[i]);
        #pragma unroll
        for (int im = 0; im < 4; ++im)
            #pragma unroll
            for (int in = 0; in < 4; ++in)
                acc[im][in] = __builtin_amdgcn_mfma_f32_16x16x32_f16(af[im], bf[in], acc[im][in], 0, 0, 0);
    }

    // epilogue: C/D layout col = lane&15, row = quad*4 + reg
    #pragma unroll
    for (int in = 0; in < 4; ++in) {
        int col = n0 + wn * 64 + in * 16 + fr;
        float bb = bias[col];
        #pragma unroll
        for (int im = 0; im < 4; ++im) {
            int rowb = m0 + wm * 64 + im * 16 + quad * 4;
            #pragma unroll
            for (int r = 0; r < 4; ++r) {
                float val = acc[im][in][r] + bb;
                if (MODE == 0) {
                    int rr = rowb + r;
                    int b = rr >> 12, l = rr & 4095, h = col >> 6, c = col & 63;
                    ((f16*)Cout)[((size_t)(((b << 4) + h) << 12) + l) * 64 + c] = (f16)val;
                } else {
                    ((float*)Cout)[(size_t)(rowb + r) * DD + col] = val;
                }
            }
        }
    }
}

// ---------------------------------------------------------------------------
// out[b][l][h*64+c] = sum_k w[bh][k] * V[b][h][(l-d_k)&4095][c], f16 in/out.
__global__ __launch_bounds__(256) void k_roll(const f16* __restrict__ V,
                                              const float* __restrict__ wts,
                                              const int* __restrict__ dls,
                                              f16* __restrict__ out) {
    int t = blockIdx.x * 256 + threadIdx.x;    // B*H*L*8 threads
    int cc = t & 7;
    int l = (t >> 3) & 4095;
    int bh = t >> 15;
    const f16* vb = V + ((size_t)bh << 18);
    float a[8] = {};
    #pragma unroll
    for (int kk = 0; kk < KTOP; ++kk) {
        float w = wts[bh * KTOP + kk];
        int d = dls[bh * KTOP + kk];
        int src = (l - d) & 4095;
        f16x8 vv = *(const f16x8*)(vb + (src << 6) + (cc << 3));
        #pragma unroll
        for (int j = 0; j < 8; ++j) a[j] += w * (float)vv[j];
    }
    f16* o = out + ((size_t)((bh >> 4) << 12) + l) * 1024 + ((bh & 15) << 6) + (cc << 3);
    f16x8 ov;
    #pragma unroll
    for (int j = 0; j < 8; ++j) ov[j] = (f16)a[j];
    *(f16x8*)o = ov;
}

// ---------------------------------------------------------------------------
extern "C" void kernel_launch(void* const* d_in, const int* in_sizes, int n_in,
                              void* d_out, int out_size, void* d_ws, size_t ws_size,
                              hipStream_t stream) {
    const float* queries = (const float*)d_in[0];
    const float* keys    = (const float*)d_in[1];
    const float* values  = (const float*)d_in[2];
    const float* Wq = (const float*)d_in[3];
    const float* bq = (const float*)d_in[4];
    const float* Wk = (const float*)d_in[5];
    const float* bk = (const float*)d_in[6];
    const float* Wv = (const float*)d_in[7];
    const float* bv = (const float*)d_in[8];
    const float* Wo = (const float*)d_in[9];
    const float* bo = (const float*)d_in[10];

    char* ws = (char*)d_ws;
    size_t off = 0;
    auto alloc = [&](size_t bytes) -> char* {
        char* p = ws + off;
        off += (bytes + 255) & ~(size_t)255;
        return p;
    };
    f16*   values_f16 = (f16*)alloc((size_t)MROWS * DD * 2);  // 33.5 MB
    f16*   Vbuf       = (f16*)alloc((size_t)MROWS * DD * 2);  // 33.5 MB
    f16*   WvT        = (f16*)alloc((size_t)DD * DD * 2);
    f16*   WoT        = (f16*)alloc((size_t)DD * DD * 2);
    float* Wqm_t      = (float*)alloc(HH * DD * 4);
    float* Wkm_t      = (float*)alloc(HH * DD * 4);
    float* bqm        = (float*)alloc(HH * 4);
    float* bkm        = (float*)alloc(HH * 4);
    float* qm         = (float*)alloc((size_t)BB * HH * LL * 4);
    float* km         = (float*)alloc((size_t)BB * HH * LL * 4);
    float* corr       = (float*)alloc((size_t)BB * HH * LL * 4);
    float* wts        = (float*)alloc(BB * HH * KTOP * 4);
    int*   dls        = (int*)alloc(BB * HH * KTOP * 4);
    f16*   out_f16    = values_f16;  // alias: values_f16 is dead after GEMM1

    k_colmeans<<<128, 256, 0, stream>>>(Wq, bq, Wk, bk, Wqm_t, Wkm_t, bqm, bkm);
    k_transpose_cvt<<<dim3(32, 32), dim3(32, 8), 0, stream>>>(Wv, WvT);
    k_transpose_cvt<<<dim3(32, 32), dim3(32, 8), 0, stream>>>(Wo, WoT);
    k_cvt_f16<<<16384, 256, 0, stream>>>(values, values_f16);
    k_means<<<1024, 256, 0, stream>>>(queries, keys, Wqm_t, Wkm_t, bqm, bkm, qm, km);
    k_corr<<<256, 256, 0, stream>>>(qm, km, corr);
    k_topk<<<64, 256, 0, stream>>>(corr, wts, dls);
    k_gemm_bt<0><<<dim3(DD / BN, MROWS / BM), 256, 0, stream>>>(values_f16, WvT, bv, Vbuf);
    k_roll<<<8192, 256, 0, stream>>>(Vbuf, wts, dls, out_f16);
    k_gemm_bt<1><<<dim3(DD / BN, MROWS / BM), 256, 0, stream>>>(out_f16, WoT, bo, d_out);
}

// Round 2
// 475.775 us; speedup vs baseline: 1.4330x; 1.4330x over previous
//
#include <hip/hip_runtime.h>
#include <hip/hip_bf16.h>
#include <cstdint>

// Problem constants (B, L, D, H from the reference)
#define BB 4
#define LL 4096
#define DD 1024
#define HH 16
#define DKH 64
#define MROWS 16384   // B*L
#define KTOP 8
#define RPB 16        // rows per k_means block (16 fp32 rows = 64 KB LDS)

typedef float f32x4 __attribute__((ext_vector_type(4)));
typedef _Float16 f16;
typedef _Float16 f16x4 __attribute__((ext_vector_type(4)));
typedef _Float16 f16x8 __attribute__((ext_vector_type(8)));

// ---------------------------------------------------------------------------
// async global->LDS (16B per lane, wave-uniform LDS base + lane*16)
__device__ __forceinline__ void gll16(const void* g, void* l) {
    __builtin_amdgcn_global_load_lds(
        (const __attribute__((address_space(1))) void*)g,
        (__attribute__((address_space(3))) void*)l, 16, 0, 0);
}

// ---------------------------------------------------------------------------
// Per-head column means of Wq/Wk (mean over DK cols of each head) -> Wqm_t[h][d]
// plus per-head means of bq/bk. Exactness here protects top-k selection.
__global__ void k_colmeans(const float* __restrict__ Wq, const float* __restrict__ bq,
                           const float* __restrict__ Wk, const float* __restrict__ bk,
                           float* __restrict__ Wqm_t, float* __restrict__ Wkm_t,
                           float* __restrict__ bqm, float* __restrict__ bkm) {
    int t = blockIdx.x * blockDim.x + threadIdx.x;   // 0..32767
    int which = t >> 14;                             // 0=q 1=k
    int idx = t & 16383;
    int d = idx >> 4;
    int h = idx & 15;
    const float* W = which ? Wk : Wq;
    const float* p = W + d * DD + h * DKH;
    float s = 0.f;
    #pragma unroll
    for (int c = 0; c < DKH; ++c) s += p[c];
    (which ? Wkm_t : Wqm_t)[h * DD + d] = s * (1.0f / DKH);
    if (d == 0) {
        const float* bb = which ? bk : bq;
        float sb = 0.f;
        for (int c = 0; c < DKH; ++c) sb += bb[h * DKH + c];
        (which ? bkm : bqm)[h] = sb * (1.0f / DKH);
    }
}

// ---------------------------------------------------------------------------
// Transpose 1024x1024 fp32 -> f16 (out[n][k] = in[k][n]) via LDS tile.
__global__ void k_transpose_cvt(const float* __restrict__ in, f16* __restrict__ out) {
    __shared__ float tile[32][33];
    int k0 = blockIdx.x * 32;
    int n0 = blockIdx.y * 32;
    int tx = threadIdx.x, ty = threadIdx.y;
    #pragma unroll
    for (int j = 0; j < 32; j += 8)
        tile[ty + j][tx] = in[(k0 + ty + j) * DD + n0 + tx];
    __syncthreads();
    #pragma unroll
    for (int j = 0; j < 32; j += 8)
        out[(n0 + ty + j) * DD + k0 + tx] = (f16)tile[tx][ty + j];
}

// fp32 -> f16, 4 elems/thread
__global__ void k_cvt_f16(const float* __restrict__ in, f16* __restrict__ out) {
    int i = blockIdx.x * blockDim.x + threadIdx.x;
    f32x4 v = ((const f32x4*)in)[i];
    f16x4 o;
    o[0] = (f16)v.x; o[1] = (f16)v.y; o[2] = (f16)v.z; o[3] = (f16)v.w;
    ((f16x4*)out)[i] = o;
}

// ---------------------------------------------------------------------------
// k_means v2: qm[bh][l], km[bh][l] in fp32.
// Block = 16 rows staged in LDS (64 KB exact, XOR-swizzled 16B chunks:
// phys_chunk = rl*256 + (c ^ (rl&7)) -> staging stores AND compute reads both
// spread evenly 8 addrs/bank-group = b128 structural minimum, no padding).
// Thread (rl=t&15, ks=(t>>4)&3, hg=t>>6): 4 heads {hg,hg+4,hg+8,hg+12} over
// 256-channel K-slice; W addresses uniform across each 16-lane group (L1
// broadcast, 1 KB live window); shfl_xor(16|32) reduces over ks.
__global__ __launch_bounds__(256) void k_means(const float* __restrict__ q, const float* __restrict__ k,
                        const float* __restrict__ Wqm_t, const float* __restrict__ Wkm_t,
                        const float* __restrict__ bqm, const float* __restrict__ bkm,
                        float* __restrict__ qm, float* __restrict__ km) {
    __shared__ f32x4 rows4[RPB * 256];   // 64 KB
    int isK = blockIdx.x & 1;
    int g = blockIdx.x >> 1;             // row group 0..1023
    const float* src = isK ? k : q;
    const float* W = isK ? Wkm_t : Wqm_t;
    const float* bm = isK ? bkm : bqm;
    float* dst = isK ? km : qm;
    int t = threadIdx.x;
    const f32x4* gsrc = (const f32x4*)src + (size_t)g * (RPB * 256);
    #pragma unroll
    for (int j = 0; j < RPB; ++j) {
        f32x4 v = gsrc[j * 256 + t];
        rows4[j * 256 + (t ^ (j & 7))] = v;
    }
    __syncthreads();
    int rl = t & 15, ks = (t >> 4) & 3, hg = t >> 6;
    int r7 = rl & 7;
    const f32x4* w0 = (const f32x4*)(W + (hg     ) * DD);
    const f32x4* w1 = (const f32x4*)(W + (hg +  4) * DD);
    const f32x4* w2 = (const f32x4*)(W + (hg +  8) * DD);
    const f32x4* w3 = (const f32x4*)(W + (hg + 12) * DD);
    const f32x4* rbase = rows4 + rl * 256;
    float a0 = 0, a1 = 0, a2 = 0, a3 = 0;
    #pragma unroll 4
    for (int i = 0; i < 64; ++i) {
        int c = ks * 64 + i;
        f32x4 r = rbase[c ^ r7];
        f32x4 x0 = w0[c], x1 = w1[c], x2 = w2[c], x3 = w3[c];
        a0 += r.x * x0.x + r.y * x0.y + r.z * x0.z + r.w * x0.w;
        a1 += r.x * x1.x + r.y * x1.y + r.z * x1.z + r.w * x1.w;
        a2 += r.x * x2.x + r.y * x2.y + r.z * x2.z + r.w * x2.w;
        a3 += r.x * x3.x + r.y * x3.y + r.z * x3.z + r.w * x3.w;
    }
    a0 += __shfl_xor(a0, 16); a0 += __shfl_xor(a0, 32);
    a1 += __shfl_xor(a1, 16); a1 += __shfl_xor(a1, 32);
    a2 += __shfl_xor(a2, 16); a2 += __shfl_xor(a2, 32);
    a3 += __shfl_xor(a3, 16); a3 += __shfl_xor(a3, 32);
    if ((t & 48) == 0) {
        int row = g * RPB + rl;
        int b = row >> 12, l = row & 4095;
        dst[((size_t)((b << 4) + hg     ) << 12) + l] = a0 + bm[hg];
        dst[((size_t)((b << 4) + hg +  4) << 12) + l] = a1 + bm[hg + 4];
        dst[((size_t)((b << 4) + hg +  8) << 12) + l] = a2 + bm[hg + 8];
        dst[((size_t)((b << 4) + hg + 12) << 12) + l] = a3 + bm[hg + 12];
    }
}

// ---------------------------------------------------------------------------
// k_corr v2: corr[bh][d] = sum_m qm[bh][(m+d)%L] * km[bh][m]
// 256 blocks x 1024 threads (4 waves/SIMD for latency hiding): thread
// (lt=t&255, ms=t>>8) does 4 lags over a 1024-m slice with the sliding
// 8-float register window; LDS partial reduction over the 4 m-slices.
__global__ __launch_bounds__(1024) void k_corr(const float* __restrict__ qm,
                                               const float* __restrict__ km,
                                               float* __restrict__ corr) {
    __shared__ float sq[LL];        // 16 KB
    __shared__ float sk[LL];        // 16 KB
    __shared__ f32x4 red[1024];     // 16 KB
    int bh = blockIdx.x >> 2;
    int lag0 = (blockIdx.x & 3) * 1024;
    const f32x4* qg = (const f32x4*)(qm + bh * LL);
    const f32x4* kg = (const f32x4*)(km + bh * LL);
    f32x4* sq4 = (f32x4*)sq;
    f32x4* sk4 = (f32x4*)sk;
    int t = threadIdx.x;
    for (int i = t; i < LL / 4; i += 1024) { sq4[i] = qg[i]; sk4[i] = kg[i]; }
    __syncthreads();
    int lt = t & 255;
    int ms = t >> 8;
    int d0 = lag0 + lt * 4;
    int m0 = ms * 1024;
    float a0 = 0, a1 = 0, a2 = 0, a3 = 0;
    f32x4 wv = sq4[((m0 + d0) & 4095) >> 2];
    float w0 = wv.x, w1 = wv.y, w2 = wv.z, w3 = wv.w;
    #pragma unroll 4
    for (int m = m0; m < m0 + 1024; m += 4) {
        f32x4 nx = sq4[((m + 4 + d0) & 4095) >> 2];
        f32x4 kv = sk4[m >> 2];
        a0 += kv.x * w0;  a1 += kv.x * w1;  a2 += kv.x * w2;  a3 += kv.x * w3;
        a0 += kv.y * w1;  a1 += kv.y * w2;  a2 += kv.y * w3;  a3 += kv.y * nx.x;
        a0 += kv.z * w2;  a1 += kv.z * w3;  a2 += kv.z * nx.x; a3 += kv.z * nx.y;
        a0 += kv.w * w3;  a1 += kv.w * nx.x; a2 += kv.w * nx.y; a3 += kv.w * nx.z;
        w0 = nx.x; w1 = nx.y; w2 = nx.z; w3 = nx.w;
    }
    f32x4 p; p.x = a0; p.y = a1; p.z = a2; p.w = a3;
    red[t] = p;
    __syncthreads();
    if (t < 256) {
        f32x4 s0 = red[t], s1 = red[256 + t], s2 = red[512 + t], s3 = red[768 + t];
        f32x4 s;
        s.x = s0.x + s1.x + s2.x + s3.x;
        s.y = s0.y + s1.y + s2.y + s3.y;
        s.z = s0.z + s1.z + s2.z + s3.z;
        s.w = s0.w + s1.w + s2.w + s3.w;
        *(f32x4*)(corr + bh * LL + lag0 + t * 4) = s;
    }
}

// ---------------------------------------------------------------------------
// top-8 (value, index) per bh with lowest-index tie-break, then softmax.
__global__ __launch_bounds__(256) void k_topk(const float* __restrict__ corr,
                                              float* __restrict__ wts, int* __restrict__ dls) {
    __shared__ float sc[LL];
    __shared__ float rv[4]; __shared__ int ri[4];
    __shared__ float topv[KTOP]; __shared__ int topi[KTOP];
    int bh = blockIdx.x;
    for (int i = threadIdx.x; i < LL; i += 256) sc[i] = corr[bh * LL + i];
    for (int kk = 0; kk < KTOP; ++kk) {
        __syncthreads();
        float bv = -1e30f; int bi = 0;
        for (int i = threadIdx.x; i < LL; i += 256) {
            float v = sc[i];
            if (v > bv) { bv = v; bi = i; }
        }
        #pragma unroll
        for (int off = 32; off; off >>= 1) {
            float ov = __shfl_down(bv, off);
            int oi = __shfl_down(bi, off);
            if (ov > bv || (ov == bv && oi < bi)) { bv = ov; bi = oi; }
        }
        int wid = threadIdx.x >> 6;
        if ((threadIdx.x & 63) == 0) { rv[wid] = bv; ri[wid] = bi; }
        __syncthreads();
        if (threadIdx.x == 0) {
            for (int w = 1; w < 4; ++w)
                if (rv[w] > bv || (rv[w] == bv && ri[w] < bi)) { bv = rv[w]; bi = ri[w]; }
            topv[kk] = bv; topi[kk] = bi;
            sc[bi] = -1e30f;
        }
    }
    __syncthreads();
    if (threadIdx.x == 0) {
        float mx = topv[0], s = 0.f, e[KTOP];
        #pragma unroll
        for (int kk = 0; kk < KTOP; ++kk) { e[kk] = __expf(topv[kk] - mx); s += e[kk]; }
        float inv = 1.0f / s;
        #pragma unroll
        for (int kk = 0; kk < KTOP; ++kk) {
            wts[bh * KTOP + kk] = e[kk] * inv;
            dls[bh * KTOP + kk] = topi[kk];
        }
    }
}

// ---------------------------------------------------------------------------
// f16 MFMA GEMM, C = A(MxK) @ BT(NxK)^T + bias. 128x128 tile, BK=32, 4 waves.
// LDS tiles stored as 16B chunks row-major with XOR swizzle kc^((row>>1)&3):
// staging stays 64B-coalesced, fragment ds_read_b128 is 2-way (free).
// MODE 0: store f16 into V[b][h][l][c] (BHLD).  MODE 1: store fp32 row-major.
#define BM 128
#define BN 128
#define BKK 32
template <int MODE>
__global__ __launch_bounds__(256) void k_gemm_bt(const f16* __restrict__ A,
                                                 const f16* __restrict__ BT,
                                                 const float* __restrict__ bias,
                                                 void* __restrict__ Cout) {
    __shared__ f16 As[BM * BKK];   // 8 KB
    __shared__ f16 Bs[BN * BKK];   // 8 KB
    const int K = DD;
    int n0 = blockIdx.x * BN;
    int m0 = blockIdx.y * BM;
    int tid = threadIdx.x;
    int lane = tid & 63;
    int wave = tid >> 6;
    int wm = wave & 1, wn = wave >> 1;

    // staging source (two passes of 256 chunks)
    int row0 = tid >> 2;                 // 0..63
    int slot = tid & 3;
    int kc0 = slot ^ ((row0 >> 1) & 3);
    int row1 = row0 + 64;                // 64..127
    int kc1 = slot ^ ((row1 >> 1) & 3);
    const f16* gA0 = A + (size_t)(m0 + row0) * K + kc0 * 8;
    const f16* gA1 = A + (size_t)(m0 + row1) * K + kc1 * 8;
    const f16* gB0 = BT + (size_t)(n0 + row0) * K + kc0 * 8;
    const f16* gB1 = BT + (size_t)(n0 + row1) * K + kc1 * 8;
    char* ldsA0 = (char*)As + wave * 1024;
    char* ldsA1 = (char*)As + 4096 + wave * 1024;
    char* ldsB0 = (char*)Bs + wave * 1024;
    char* ldsB1 = (char*)Bs + 4096 + wave * 1024;

    // fragment LDS element offsets (constant per lane)
    int fr = lane & 15;
    int quad = lane >> 4;
    int a_off[4], b_off[4];
    #pragma unroll
    for (int i = 0; i < 4; ++i) {
        int ra = wm * 64 + i * 16 + fr;
        a_off[i] = (ra * 4 + (quad ^ ((ra >> 1) & 3))) * 8;
        int rb = wn * 64 + i * 16 + fr;
        b_off[i] = (rb * 4 + (quad ^ ((rb >> 1) & 3))) * 8;
    }

    f32x4 acc[4][4] = {};
    for (int kt = 0; kt < K; kt += BKK) {
        __syncthreads();
        gll16(gA0, ldsA0);
        gll16(gA1, ldsA1);
        gll16(gB0, ldsB0);
        gll16(gB1, ldsB1);
        gA0 += BKK; gA1 += BKK; gB0 += BKK; gB1 += BKK;
        __syncthreads();
        f16x8 af[4], bf[4];
        #pragma unroll
        for (int i = 0; i < 4; ++i) af[i] = *(const f16x8*)(As + a_off[i]);
        #pragma unroll
        for (int i = 0; i < 4; ++i) bf[i] = *(const f16x8*)(Bs + b_off[i]);
        #pragma unroll
        for (int im = 0; im < 4; ++im)
            #pragma unroll
            for (int in = 0; in < 4; ++in)
                acc[im][in] = __builtin_amdgcn_mfma_f32_16x16x32_f16(af[im], bf[in], acc[im][in], 0, 0, 0);
    }

    // epilogue: C/D layout col = lane&15, row = quad*4 + reg
    #pragma unroll
    for (int in = 0; in < 4; ++in) {
        int col = n0 + wn * 64 + in * 16 + fr;
        float bb = bias[col];
        #pragma unroll
        for (int im = 0; im < 4; ++im) {
            int rowb = m0 + wm * 64 + im * 16 + quad * 4;
            #pragma unroll
            for (int r = 0; r < 4; ++r) {
                float val = acc[im][in][r] + bb;
                if (MODE == 0) {
                    int rr = rowb + r;
                    int b = rr >> 12, l = rr & 4095, h = col >> 6, c = col & 63;
                    ((f16*)Cout)[((size_t)(((b << 4) + h) << 12) + l) * 64 + c] = (f16)val;
                } else {
                    ((float*)Cout)[(size_t)(rowb + r) * DD + col] = val;
                }
            }
        }
    }
}

// ---------------------------------------------------------------------------
// out[b][l][h*64+c] = sum_k w[bh][k] * V[b][h][(l-d_k)&4095][c], f16 in/out.
__global__ __launch_bounds__(256) void k_roll(const f16* __restrict__ V,
                                              const float* __restrict__ wts,
                                              const int* __restrict__ dls,
                                              f16* __restrict__ out) {
    int t = blockIdx.x * 256 + threadIdx.x;    // B*H*L*8 threads
    int cc = t & 7;
    int l = (t >> 3) & 4095;
    int bh = t >> 15;
    const f16* vb = V + ((size_t)bh << 18);
    float a[8] = {};
    #pragma unroll
    for (int kk = 0; kk < KTOP; ++kk) {
        float w = wts[bh * KTOP + kk];
        int d = dls[bh * KTOP + kk];
        int src = (l - d) & 4095;
        f16x8 vv = *(const f16x8*)(vb + (src << 6) + (cc << 3));
        #pragma unroll
        for (int j = 0; j < 8; ++j) a[j] += w * (float)vv[j];
    }
    f16* o = out + ((size_t)((bh >> 4) << 12) + l) * 1024 + ((bh & 15) << 6) + (cc << 3);
    f16x8 ov;
    #pragma unroll
    for (int j = 0; j < 8; ++j) ov[j] = (f16)a[j];
    *(f16x8*)o = ov;
}

// ---------------------------------------------------------------------------
extern "C" void kernel_launch(void* const* d_in, const int* in_sizes, int n_in,
                              void* d_out, int out_size, void* d_ws, size_t ws_size,
                              hipStream_t stream) {
    const float* queries = (const float*)d_in[0];
    const float* keys    = (const float*)d_in[1];
    const float* values  = (const float*)d_in[2];
    const float* Wq = (const float*)d_in[3];
    const float* bq = (const float*)d_in[4];
    const float* Wk = (const float*)d_in[5];
    const float* bk = (const float*)d_in[6];
    const float* Wv = (const float*)d_in[7];
    const float* bv = (const float*)d_in[8];
    const float* Wo = (const float*)d_in[9];
    const float* bo = (const float*)d_in[10];

    char* ws = (char*)d_ws;
    size_t off = 0;
    auto alloc = [&](size_t bytes) -> char* {
        char* p = ws + off;
        off += (bytes + 255) & ~(size_t)255;
        return p;
    };
    f16*   values_f16 = (f16*)alloc((size_t)MROWS * DD * 2);  // 33.5 MB
    f16*   Vbuf       = (f16*)alloc((size_t)MROWS * DD * 2);  // 33.5 MB
    f16*   WvT        = (f16*)alloc((size_t)DD * DD * 2);
    f16*   WoT        = (f16*)alloc((size_t)DD * DD * 2);
    float* Wqm_t      = (float*)alloc(HH * DD * 4);
    float* Wkm_t      = (float*)alloc(HH * DD * 4);
    float* bqm        = (float*)alloc(HH * 4);
    float* bkm        = (float*)alloc(HH * 4);
    float* qm         = (float*)alloc((size_t)BB * HH * LL * 4);
    float* km         = (float*)alloc((size_t)BB * HH * LL * 4);
    float* corr       = (float*)alloc((size_t)BB * HH * LL * 4);
    float* wts        = (float*)alloc(BB * HH * KTOP * 4);
    int*   dls        = (int*)alloc(BB * HH * KTOP * 4);
    f16*   out_f16    = values_f16;  // alias: values_f16 is dead after GEMM1

    k_colmeans<<<128, 256, 0, stream>>>(Wq, bq, Wk, bk, Wqm_t, Wkm_t, bqm, bkm);
    k_transpose_cvt<<<dim3(32, 32), dim3(32, 8), 0, stream>>>(Wv, WvT);
    k_transpose_cvt<<<dim3(32, 32), dim3(32, 8), 0, stream>>>(Wo, WoT);
    k_cvt_f16<<<16384, 256, 0, stream>>>(values, values_f16);
    k_means<<<2048, 256, 0, stream>>>(queries, keys, Wqm_t, Wkm_t, bqm, bkm, qm, km);
    k_corr<<<256, 1024, 0, stream>>>(qm, km, corr);
    k_topk<<<64, 256, 0, stream>>>(corr, wts, dls);
    k_gemm_bt<0><<<dim3(DD / BN, MROWS / BM), 256, 0, stream>>>(values_f16, WvT, bv, Vbuf);
    k_roll<<<8192, 256, 0, stream>>>(Vbuf, wts, dls, out_f16);
    k_gemm_bt<1><<<dim3(DD / BN, MROWS / BM), 256, 0, stream>>>(out_f16, WoT, bo, d_out);
}

// Round 4
// 445.024 us; speedup vs baseline: 1.5320x; 1.0691x over previous
//
#include <hip/hip_runtime.h>
#include <hip/hip_bf16.h>
#include <cstdint>

// Problem constants (B, L, D, H from the reference)
#define BB 4
#define LL 4096
#define DD 1024
#define HH 16
#define DKH 64
#define MROWS 16384   // B*L
#define KTOP 8
#define RPB 16        // rows per k_means block

typedef float f32x4 __attribute__((ext_vector_type(4)));
typedef _Float16 f16;
typedef _Float16 f16x4 __attribute__((ext_vector_type(4)));
typedef _Float16 f16x8 __attribute__((ext_vector_type(8)));

// ---------------------------------------------------------------------------
// async global->LDS (16B per lane, wave-uniform LDS base + lane*16)
__device__ __forceinline__ void gll16(const void* g, void* l) {
    __builtin_amdgcn_global_load_lds(
        (const __attribute__((address_space(1))) void*)g,
        (__attribute__((address_space(3))) void*)l, 16, 0, 0);
}

// ---------------------------------------------------------------------------
// Per-head column means of Wq/Wk (mean over DK cols of each head) -> Wqm_t[h][d]
// plus per-head means of bq/bk. Exactness here protects top-k selection.
__global__ void k_colmeans(const float* __restrict__ Wq, const float* __restrict__ bq,
                           const float* __restrict__ Wk, const float* __restrict__ bk,
                           float* __restrict__ Wqm_t, float* __restrict__ Wkm_t,
                           float* __restrict__ bqm, float* __restrict__ bkm) {
    int t = blockIdx.x * blockDim.x + threadIdx.x;   // 0..32767
    int which = t >> 14;                             // 0=q 1=k
    int idx = t & 16383;
    int d = idx >> 4;
    int h = idx & 15;
    const float* W = which ? Wk : Wq;
    const float* p = W + d * DD + h * DKH;
    float s = 0.f;
    #pragma unroll
    for (int c = 0; c < DKH; ++c) s += p[c];
    (which ? Wkm_t : Wqm_t)[h * DD + d] = s * (1.0f / DKH);
    if (d == 0) {
        const float* bb = which ? bk : bq;
        float sb = 0.f;
        for (int c = 0; c < DKH; ++c) sb += bb[h * DKH + c];
        (which ? bkm : bqm)[h] = sb * (1.0f / DKH);
    }
}

// ---------------------------------------------------------------------------
// Transpose 1024x1024 fp32 -> f16 (out[n][k] = in[k][n]) via LDS tile.
__global__ void k_transpose_cvt(const float* __restrict__ in, f16* __restrict__ out) {
    __shared__ float tile[32][33];
    int k0 = blockIdx.x * 32;
    int n0 = blockIdx.y * 32;
    int tx = threadIdx.x, ty = threadIdx.y;
    #pragma unroll
    for (int j = 0; j < 32; j += 8)
        tile[ty + j][tx] = in[(k0 + ty + j) * DD + n0 + tx];
    __syncthreads();
    #pragma unroll
    for (int j = 0; j < 32; j += 8)
        out[(n0 + ty + j) * DD + k0 + tx] = (f16)tile[tx][ty + j];
}

// fp32 -> f16, 4 elems/thread
__global__ void k_cvt_f16(const float* __restrict__ in, f16* __restrict__ out) {
    int i = blockIdx.x * blockDim.x + threadIdx.x;
    f32x4 v = ((const f32x4*)in)[i];
    f16x4 o;
    o[0] = (f16)v.x; o[1] = (f16)v.y; o[2] = (f16)v.z; o[3] = (f16)v.w;
    ((f16x4*)out)[i] = o;
}

// ---------------------------------------------------------------------------
// k_means v3b: qm[bh][l], km[bh][l] in fp32. Zero staging; W in registers.
// Thread (wave w, lane l) owns 4 fixed cols c = w*256 + l*4 and ALL 16 heads
// (W frag = 16 f32x4 = 64 VGPRs, loaded once per block, L2-resident).
// Block streams RPB=16 rows: coalesced 4 KB f32x4 row loads, 16 f32x4 FMAs,
// then exchange-halving butterfly over lane bits 0..3 (KEEP the half picked
// by my lane bit, SHUFFLE the other half — partner's send is my kept head,
// heads never mix; kept head bit_j = lane bit_j so lane l ends with head
// l&15), then xor 16/32 sums the wave's four 64-col groups. One 4 KB LDS
// array + single barrier combines the 4 waves.
__global__ __launch_bounds__(256, 4) void k_means(const float* __restrict__ q, const float* __restrict__ k,
                        const float* __restrict__ Wqm_t, const float* __restrict__ Wkm_t,
                        const float* __restrict__ bqm, const float* __restrict__ bkm,
                        float* __restrict__ qm, float* __restrict__ km) {
    __shared__ float lred[RPB * 64];   // 4 KB: [row][wave*16+head]
    int isK = blockIdx.x & 1;
    int rb  = blockIdx.x >> 1;            // 0..1023
    const float* src = isK ? k : q;
    const float* W   = isK ? Wkm_t : Wqm_t;
    const float* bm  = isK ? bkm : bqm;
    float* dst = isK ? km : qm;
    int t = threadIdx.x;
    int wavei = t >> 6, lane = t & 63;
    int c = wavei * 256 + lane * 4;       // this thread's 4 columns
    f32x4 wr[16];
    #pragma unroll
    for (int h = 0; h < 16; ++h) wr[h] = *(const f32x4*)(W + h * DD + c);
    const float* rbase = src + (size_t)rb * RPB * DD + c;
    #pragma unroll 2
    for (int r = 0; r < RPB; ++r) {
        f32x4 rv = *(const f32x4*)(rbase + r * DD);
        float v[16];
        #pragma unroll
        for (int h = 0; h < 16; ++h)
            v[h] = rv.x * wr[h].x + rv.y * wr[h].y + rv.z * wr[h].z + rv.w * wr[h].w;
        float u[8];
        #pragma unroll
        for (int i = 0; i < 8; ++i) {
            float keep = (lane & 1) ? v[2*i+1] : v[2*i];
            float send = (lane & 1) ? v[2*i]   : v[2*i+1];
            u[i] = keep + __shfl_xor(send, 1);
        }
        float w2[4];
        #pragma unroll
        for (int i = 0; i < 4; ++i) {
            float keep = (lane & 2) ? u[2*i+1] : u[2*i];
            float send = (lane & 2) ? u[2*i]   : u[2*i+1];
            w2[i] = keep + __shfl_xor(send, 2);
        }
        float y[2];
        #pragma unroll
        for (int i = 0; i < 2; ++i) {
            float keep = (lane & 4) ? w2[2*i+1] : w2[2*i];
            float send = (lane & 4) ? w2[2*i]   : w2[2*i+1];
            y[i] = keep + __shfl_xor(send, 4);
        }
        {
            float keep = (lane & 8) ? y[1] : y[0];
            float send = (lane & 8) ? y[0] : y[1];
            float z = keep + __shfl_xor(send, 8);
            z += __shfl_xor(z, 16);
            z += __shfl_xor(z, 32);
            if (lane < 16) lred[r * 64 + wavei * 16 + lane] = z;
        }
    }
    __syncthreads();
    // combine: 256 outputs (16 rows x 16 heads), one per thread
    int rr = t >> 4, h = t & 15;
    float s = lred[rr * 64 + h] + lred[rr * 64 + 16 + h]
            + lred[rr * 64 + 32 + h] + lred[rr * 64 + 48 + h] + bm[h];
    int row = rb * RPB + rr;
    int b = row >> 12, l = row & 4095;
    dst[((size_t)((b << 4) + h) << 12) + l] = s;
}

// ---------------------------------------------------------------------------
// k_corr v2: corr[bh][d] = sum_m qm[bh][(m+d)%L] * km[bh][m]
// 256 blocks x 1024 threads (4 waves/SIMD for latency hiding): thread
// (lt=t&255, ms=t>>8) does 4 lags over a 1024-m slice with the sliding
// 8-float register window; LDS partial reduction over the 4 m-slices.
__global__ __launch_bounds__(1024) void k_corr(const float* __restrict__ qm,
                                               const float* __restrict__ km,
                                               float* __restrict__ corr) {
    __shared__ float sq[LL];        // 16 KB
    __shared__ float sk[LL];        // 16 KB
    __shared__ f32x4 red[1024];     // 16 KB
    int bh = blockIdx.x >> 2;
    int lag0 = (blockIdx.x & 3) * 1024;
    const f32x4* qg = (const f32x4*)(qm + bh * LL);
    const f32x4* kg = (const f32x4*)(km + bh * LL);
    f32x4* sq4 = (f32x4*)sq;
    f32x4* sk4 = (f32x4*)sk;
    int t = threadIdx.x;
    for (int i = t; i < LL / 4; i += 1024) { sq4[i] = qg[i]; sk4[i] = kg[i]; }
    __syncthreads();
    int lt = t & 255;
    int ms = t >> 8;
    int d0 = lag0 + lt * 4;
    int m0 = ms * 1024;
    float a0 = 0, a1 = 0, a2 = 0, a3 = 0;
    f32x4 wv = sq4[((m0 + d0) & 4095) >> 2];
    float w0 = wv.x, w1 = wv.y, w2 = wv.z, w3 = wv.w;
    #pragma unroll 4
    for (int m = m0; m < m0 + 1024; m += 4) {
        f32x4 nx = sq4[((m + 4 + d0) & 4095) >> 2];
        f32x4 kv = sk4[m >> 2];
        a0 += kv.x * w0;  a1 += kv.x * w1;  a2 += kv.x * w2;  a3 += kv.x * w3;
        a0 += kv.y * w1;  a1 += kv.y * w2;  a2 += kv.y * w3;  a3 += kv.y * nx.x;
        a0 += kv.z * w2;  a1 += kv.z * w3;  a2 += kv.z * nx.x; a3 += kv.z * nx.y;
        a0 += kv.w * w3;  a1 += kv.w * nx.x; a2 += kv.w * nx.y; a3 += kv.w * nx.z;
        w0 = nx.x; w1 = nx.y; w2 = nx.z; w3 = nx.w;
    }
    f32x4 p; p.x = a0; p.y = a1; p.z = a2; p.w = a3;
    red[t] = p;
    __syncthreads();
    if (t < 256) {
        f32x4 s0 = red[t], s1 = red[256 + t], s2 = red[512 + t], s3 = red[768 + t];
        f32x4 s;
        s.x = s0.x + s1.x + s2.x + s3.x;
        s.y = s0.y + s1.y + s2.y + s3.y;
        s.z = s0.z + s1.z + s2.z + s3.z;
        s.w = s0.w + s1.w + s2.w + s3.w;
        *(f32x4*)(corr + bh * LL + lag0 + t * 4) = s;
    }
}

// ---------------------------------------------------------------------------
// top-8 (value, index) per bh with lowest-index tie-break, then softmax.
__global__ __launch_bounds__(256) void k_topk(const float* __restrict__ corr,
                                              float* __restrict__ wts, int* __restrict__ dls) {
    __shared__ float sc[LL];
    __shared__ float rv[4]; __shared__ int ri[4];
    __shared__ float topv[KTOP]; __shared__ int topi[KTOP];
    int bh = blockIdx.x;
    for (int i = threadIdx.x; i < LL; i += 256) sc[i] = corr[bh * LL + i];
    for (int kk = 0; kk < KTOP; ++kk) {
        __syncthreads();
        float bv = -1e30f; int bi = 0;
        for (int i = threadIdx.x; i < LL; i += 256) {
            float v = sc[i];
            if (v > bv) { bv = v; bi = i; }
        }
        #pragma unroll
        for (int off = 32; off; off >>= 1) {
            float ov = __shfl_down(bv, off);
            int oi = __shfl_down(bi, off);
            if (ov > bv || (ov == bv && oi < bi)) { bv = ov; bi = oi; }
        }
        int wid = threadIdx.x >> 6;
        if ((threadIdx.x & 63) == 0) { rv[wid] = bv; ri[wid] = bi; }
        __syncthreads();
        if (threadIdx.x == 0) {
            for (int w = 1; w < 4; ++w)
                if (rv[w] > bv || (rv[w] == bv && ri[w] < bi)) { bv = rv[w]; bi = ri[w]; }
            topv[kk] = bv; topi[kk] = bi;
            sc[bi] = -1e30f;
        }
    }
    __syncthreads();
    if (threadIdx.x == 0) {
        float mx = topv[0], s = 0.f, e[KTOP];
        #pragma unroll
        for (int kk = 0; kk < KTOP; ++kk) { e[kk] = __expf(topv[kk] - mx); s += e[kk]; }
        float inv = 1.0f / s;
        #pragma unroll
        for (int kk = 0; kk < KTOP; ++kk) {
            wts[bh * KTOP + kk] = e[kk] * inv;
            dls[bh * KTOP + kk] = topi[kk];
        }
    }
}

// ---------------------------------------------------------------------------
// f16 MFMA GEMM, C = A(MxK) @ BT(NxK)^T + bias. 128x128 tile, BK=32, 4 waves.
// LDS tiles stored as 16B chunks row-major with XOR swizzle kc^((row>>1)&3):
// staging stays 64B-coalesced, fragment ds_read_b128 is 2-way (free).
// MODE 0: store f16 into V[b][h][l][c] (BHLD).  MODE 1: store fp32 row-major.
#define BM 128
#define BN 128
#define BKK 32
template <int MODE>
__global__ __launch_bounds__(256) void k_gemm_bt(const f16* __restrict__ A,
                                                 const f16* __restrict__ BT,
                                                 const float* __restrict__ bias,
                                                 void* __restrict__ Cout) {
    __shared__ f16 As[BM * BKK];   // 8 KB
    __shared__ f16 Bs[BN * BKK];   // 8 KB
    const int K = DD;
    int n0 = blockIdx.x * BN;
    int m0 = blockIdx.y * BM;
    int tid = threadIdx.x;
    int lane = tid & 63;
    int wave = tid >> 6;
    int wm = wave & 1, wn = wave >> 1;

    // staging source (two passes of 256 chunks)
    int row0 = tid >> 2;                 // 0..63
    int slot = tid & 3;
    int kc0 = slot ^ ((row0 >> 1) & 3);
    int row1 = row0 + 64;                // 64..127
    int kc1 = slot ^ ((row1 >> 1) & 3);
    const f16* gA0 = A + (size_t)(m0 + row0) * K + kc0 * 8;
    const f16* gA1 = A + (size_t)(m0 + row1) * K + kc1 * 8;
    const f16* gB0 = BT + (size_t)(n0 + row0) * K + kc0 * 8;
    const f16* gB1 = BT + (size_t)(n0 + row1) * K + kc1 * 8;
    char* ldsA0 = (char*)As + wave * 1024;
    char* ldsA1 = (char*)As + 4096 + wave * 1024;
    char* ldsB0 = (char*)Bs + wave * 1024;
    char* ldsB1 = (char*)Bs + 4096 + wave * 1024;

    // fragment LDS element offsets (constant per lane)
    int fr = lane & 15;
    int quad = lane >> 4;
    int a_off[4], b_off[4];
    #pragma unroll
    for (int i = 0; i < 4; ++i) {
        int ra = wm * 64 + i * 16 + fr;
        a_off[i] = (ra * 4 + (quad ^ ((ra >> 1) & 3))) * 8;
        int rb = wn * 64 + i * 16 + fr;
        b_off[i] = (rb * 4 + (quad ^ ((rb >> 1) & 3))) * 8;
    }

    f32x4 acc[4][4] = {};
    for (int kt = 0; kt < K; kt += BKK) {
        __syncthreads();
        gll16(gA0, ldsA0);
        gll16(gA1, ldsA1);
        gll16(gB0, ldsB0);
        gll16(gB1, ldsB1);
        gA0 += BKK; gA1 += BKK; gB0 += BKK; gB1 += BKK;
        __syncthreads();
        f16x8 af[4], bf[4];
        #pragma unroll
        for (int i = 0; i < 4; ++i) af[i] = *(const f16x8*)(As + a_off[i]);
        #pragma unroll
        for (int i = 0; i < 4; ++i) bf[i] = *(const f16x8*)(Bs + b_off[i]);
        #pragma unroll
        for (int im = 0; im < 4; ++im)
            #pragma unroll
            for (int in = 0; in < 4; ++in)
                acc[im][in] = __builtin_amdgcn_mfma_f32_16x16x32_f16(af[im], bf[in], acc[im][in], 0, 0, 0);
    }

    // epilogue: C/D layout col = lane&15, row = quad*4 + reg
    #pragma unroll
    for (int in = 0; in < 4; ++in) {
        int col = n0 + wn * 64 + in * 16 + fr;
        float bb = bias[col];
        #pragma unroll
        for (int im = 0; im < 4; ++im) {
            int rowb = m0 + wm * 64 + im * 16 + quad * 4;
            #pragma unroll
            for (int r = 0; r < 4; ++r) {
                float val = acc[im][in][r] + bb;
                if (MODE == 0) {
                    int rr = rowb + r;
                    int b = rr >> 12, l = rr & 4095, h = col >> 6, c = col & 63;
                    ((f16*)Cout)[((size_t)(((b << 4) + h) << 12) + l) * 64 + c] = (f16)val;
                } else {
                    ((float*)Cout)[(size_t)(rowb + r) * DD + col] = val;
                }
            }
        }
    }
}

// ---------------------------------------------------------------------------
// out[b][l][h*64+c] = sum_k w[bh][k] * V[b][h][(l-d_k)&4095][c], f16 in/out.
__global__ __launch_bounds__(256) void k_roll(const f16* __restrict__ V,
                                              const float* __restrict__ wts,
                                              const int* __restrict__ dls,
                                              f16* __restrict__ out) {
    int t = blockIdx.x * 256 + threadIdx.x;    // B*H*L*8 threads
    int cc = t & 7;
    int l = (t >> 3) & 4095;
    int bh = t >> 15;
    const f16* vb = V + ((size_t)bh << 18);
    float a[8] = {};
    #pragma unroll
    for (int kk = 0; kk < KTOP; ++kk) {
        float w = wts[bh * KTOP + kk];
        int d = dls[bh * KTOP + kk];
        int src = (l - d) & 4095;
        f16x8 vv = *(const f16x8*)(vb + (src << 6) + (cc << 3));
        #pragma unroll
        for (int j = 0; j < 8; ++j) a[j] += w * (float)vv[j];
    }
    f16* o = out + ((size_t)((bh >> 4) << 12) + l) * 1024 + ((bh & 15) << 6) + (cc << 3);
    f16x8 ov;
    #pragma unroll
    for (int j = 0; j < 8; ++j) ov[j] = (f16)a[j];
    *(f16x8*)o = ov;
}

// ---------------------------------------------------------------------------
extern "C" void kernel_launch(void* const* d_in, const int* in_sizes, int n_in,
                              void* d_out, int out_size, void* d_ws, size_t ws_size,
                              hipStream_t stream) {
    const float* queries = (const float*)d_in[0];
    const float* keys    = (const float*)d_in[1];
    const float* values  = (const float*)d_in[2];
    const float* Wq = (const float*)d_in[3];
    const float* bq = (const float*)d_in[4];
    const float* Wk = (const float*)d_in[5];
    const float* bk = (const float*)d_in[6];
    const float* Wv = (const float*)d_in[7];
    const float* bv = (const float*)d_in[8];
    const float* Wo = (const float*)d_in[9];
    const float* bo = (const float*)d_in[10];

    char* ws = (char*)d_ws;
    size_t off = 0;
    auto alloc = [&](size_t bytes) -> char* {
        char* p = ws + off;
        off += (bytes + 255) & ~(size_t)255;
        return p;
    };
    f16*   values_f16 = (f16*)alloc((size_t)MROWS * DD * 2);  // 33.5 MB
    f16*   Vbuf       = (f16*)alloc((size_t)MROWS * DD * 2);  // 33.5 MB
    f16*   WvT        = (f16*)alloc((size_t)DD * DD * 2);
    f16*   WoT        = (f16*)alloc((size_t)DD * DD * 2);
    float* Wqm_t      = (float*)alloc(HH * DD * 4);
    float* Wkm_t      = (float*)alloc(HH * DD * 4);
    float* bqm        = (float*)alloc(HH * 4);
    float* bkm        = (float*)alloc(HH * 4);
    float* qm         = (float*)alloc((size_t)BB * HH * LL * 4);
    float* km         = (float*)alloc((size_t)BB * HH * LL * 4);
    float* corr       = (float*)alloc((size_t)BB * HH * LL * 4);
    float* wts        = (float*)alloc(BB * HH * KTOP * 4);
    int*   dls        = (int*)alloc(BB * HH * KTOP * 4);
    f16*   out_f16    = values_f16;  // alias: values_f16 is dead after GEMM1

    k_colmeans<<<128, 256, 0, stream>>>(Wq, bq, Wk, bk, Wqm_t, Wkm_t, bqm, bkm);
    k_transpose_cvt<<<dim3(32, 32), dim3(32, 8), 0, stream>>>(Wv, WvT);
    k_transpose_cvt<<<dim3(32, 32), dim3(32, 8), 0, stream>>>(Wo, WoT);
    k_cvt_f16<<<16384, 256, 0, stream>>>(values, values_f16);
    k_means<<<2048, 256, 0, stream>>>(queries, keys, Wqm_t, Wkm_t, bqm, bkm, qm, km);
    k_corr<<<256, 1024, 0, stream>>>(qm, km, corr);
    k_topk<<<64, 256, 0, stream>>>(corr, wts, dls);
    k_gemm_bt<0><<<dim3(DD / BN, MROWS / BM), 256, 0, stream>>>(values_f16, WvT, bv, Vbuf);
    k_roll<<<8192, 256, 0, stream>>>(Vbuf, wts, dls, out_f16);
    k_gemm_bt<1><<<dim3(DD / BN, MROWS / BM), 256, 0, stream>>>(out_f16, WoT, bo, d_out);
}